// Round 5
// baseline (430.796 us; speedup 1.0000x reference)
//
#include <hip/hip_runtime.h>
#include <hip/hip_bf16.h>

// B=4, L=4096, D=1024; M = B*L = 16384. ALL I/O IS FP32.
// Live path: h = (x@Wp[:,0:D]) * sigmoid(x@Wp[:,2D:3D]); out = h@W_out + b_out
// Internals: bf16 MFMA, fp32 accumulation.
//
// Round-5: NO-LDS GEMMs. Working set is cache-resident (weights 4+2 MB << LLC;
// per-XCD X/H panels ~2MB ~ L2 via T1 swizzle), so LDS staging was pure
// overhead (guide mistake #7): round-4 PMC showed the barrier-locked
// read-burst/MFMA-burst alternation costing ~2x the MFMA floor.
// Now: fragments load straight from global with the SAME lane mapping the
// MFMA needs (row = frag_row + lane&15, k = (lane>>4)*8), K=32 per iter,
// no barriers, no staging, no inline asm -- compiler emits counted vmcnt
// for the visible def-use chains. Intra-block fragment redundancy (4 waves
// share A rows, 2 share B rows) is served by L1.
//
// Memory plan (ws_size-adaptive, branch constant across calls => graph-safe):
//   ws shorts [0,3M)   : WgT | WoT | WoutT bf16 panels (6 MB)
//   BIG ws (>=38 MB)   : H (16M shorts) entirely at ws+3M; single gemm2 launch.
//   SMALL ws           : H rows 0..8191 -> d_out shorts [16M,24M);
//                        H rows 8192..  -> ws+3M; two sequential gemm2 halves.
//   d_out shorts [0,16M): Xbf16 during phases 1-3, then fp32 out rows 0..8191.

#define MTOT 16384
#define DM   1024
#define MEG  (1024 * 1024)

typedef __bf16 bf16x8 __attribute__((ext_vector_type(8)));
typedef float  f32x4  __attribute__((ext_vector_type(4)));

static __device__ __forceinline__ unsigned short f2bf(float f) {
    __hip_bfloat16 h = __float2bfloat16(f);
    return *(unsigned short*)&h;
}

// ---------------- x (fp32) -> Xbf16 ------------------------------------------
__global__ __launch_bounds__(256)
void conv_x(const float* __restrict__ x, unsigned short* __restrict__ dst) {
    const size_t i = ((size_t)blockIdx.x * 256 + threadIdx.x) * 8;
    const f32x4 a = *(const f32x4*)(x + i);
    const f32x4 b = *(const f32x4*)(x + i + 4);
    __align__(16) unsigned short o[8];
    o[0] = f2bf(a[0]); o[1] = f2bf(a[1]); o[2] = f2bf(a[2]); o[3] = f2bf(a[3]);
    o[4] = f2bf(b[0]); o[5] = f2bf(b[1]); o[6] = f2bf(b[2]); o[7] = f2bf(b[3]);
    *(uint4*)(dst + i) = *(const uint4*)o;
}

// -------- weight transpose+convert: dst[n][k] = bf16(src[k][coff+n]) ---------
__global__ void transpose_w(const float* __restrict__ Wproj, const float* __restrict__ Wout,
                            unsigned short* __restrict__ dst0) {
    __shared__ unsigned short t[32][33];
    const int z = blockIdx.z;
    const float* src;
    unsigned short* dst;
    int ld, coff;
    if (z == 0)      { src = Wproj; ld = 3072; coff = 0;    dst = dst0; }
    else if (z == 1) { src = Wproj; ld = 3072; coff = 2048; dst = dst0 + MEG; }
    else             { src = Wout;  ld = 1024; coff = 0;    dst = dst0 + 2 * MEG; }
    const int k0 = blockIdx.x * 32;
    const int n0 = blockIdx.y * 32;
    const int tx = threadIdx.x, ty = threadIdx.y;
    for (int i = ty; i < 32; i += 8)
        t[i][tx] = f2bf(src[(size_t)(k0 + i) * ld + coff + n0 + tx]);
    __syncthreads();
    for (int i = ty; i < 32; i += 8)
        dst[(size_t)(n0 + i) * DM + k0 + tx] = t[tx][i];
}

// ---------- GEMM1 fused: H = (X@Wg + bg) * sigmoid(X@Wo + bo) ---------------
// 512 thr / 8 waves (2M x 4N); BM=256, BN=128 per matrix; K=32 per iter.
// Per wave: rows wm*64 + h*128 + il*16 (h=0,1; il=0..3), cols wn*16 + jl*64.
// Per iter: 8 A-frag + 4 B-frag global dwordx4 loads, 32 MFMA. No LDS.
__global__ __launch_bounds__(512)
void gemm1_fused(const unsigned short* __restrict__ X,
                 const unsigned short* __restrict__ WgT,
                 const unsigned short* __restrict__ WoT,
                 const float* __restrict__ bproj,
                 unsigned short* __restrict__ Hlo,
                 unsigned short* __restrict__ Hhi) {
    const int tid  = threadIdx.x;
    const int wave = tid >> 6;
    const int lane = tid & 63;
    const int wm = wave & 1;
    const int wn = wave >> 1;

    // T1: bijective XCD swizzle (512 blocks); consecutive swz share the m-panel,
    // each XCD owns a distinct m-range -> X panels stay XCD-L2-local.
    const int bid = blockIdx.x;
    const int swz = (bid & 7) * 64 + (bid >> 3);
    const int m0 = (swz >> 3) * 256;
    const int n0 = (swz & 7) * 128;

    unsigned short* __restrict__ H =
        (m0 < 8192) ? Hlo : (Hhi - (size_t)8192 * DM);

    // MFMA fragment lane mapping: row = frag_row + (lane&15), k = (lane>>4)*8
    const int rA = lane & 15;
    const int kq = (lane >> 4) * 8;          // k-element offset within K=32

    const char* pA  = (const char*)X   + ((size_t)(m0 + wm * 64 + rA) * DM + kq) * 2;
    const char* pBg = (const char*)WgT + ((size_t)(n0 + wn * 16 + rA) * DM + kq) * 2;
    const char* pBo = (const char*)WoT + ((size_t)(n0 + wn * 16 + rA) * DM + kq) * 2;

    f32x4 aG[2][4][2], aO[2][4][2];
#pragma unroll
    for (int h = 0; h < 2; ++h)
#pragma unroll
        for (int il = 0; il < 4; ++il)
#pragma unroll
            for (int jl = 0; jl < 2; ++jl) {
                aG[h][il][jl] = (f32x4){0.f, 0.f, 0.f, 0.f};
                aO[h][il][jl] = (f32x4){0.f, 0.f, 0.f, 0.f};
            }

#pragma unroll 1
    for (int kt = 0; kt < 32; ++kt) {
        const int kb = kt * 64;              // 32 bf16 = 64 bytes per iter
        bf16x8 fa[2][4], fbg[2], fbo[2];
#pragma unroll
        for (int h = 0; h < 2; ++h)
#pragma unroll
            for (int il = 0; il < 4; ++il)
                fa[h][il] = *(const bf16x8*)(pA + (size_t)(h * 128 + il * 16) * 2048 + kb);
#pragma unroll
        for (int jl = 0; jl < 2; ++jl) {
            fbg[jl] = *(const bf16x8*)(pBg + (size_t)(jl * 64) * 2048 + kb);
            fbo[jl] = *(const bf16x8*)(pBo + (size_t)(jl * 64) * 2048 + kb);
        }
#pragma unroll
        for (int h = 0; h < 2; ++h)
#pragma unroll
            for (int il = 0; il < 4; ++il)
#pragma unroll
                for (int jl = 0; jl < 2; ++jl) {
                    aG[h][il][jl] = __builtin_amdgcn_mfma_f32_16x16x32_bf16(fa[h][il], fbg[jl], aG[h][il][jl], 0, 0, 0);
                    aO[h][il][jl] = __builtin_amdgcn_mfma_f32_16x16x32_bf16(fa[h][il], fbo[jl], aO[h][il][jl], 0, 0, 0);
                }
    }

    const int colL = lane & 15;
    const int rowQ = (lane >> 4) * 4;
#pragma unroll
    for (int jl = 0; jl < 2; ++jl) {
        const int n = n0 + wn * 16 + jl * 64 + colL;
        const float bgv = bproj[n];
        const float bov = bproj[2048 + n];
#pragma unroll
        for (int h = 0; h < 2; ++h)
#pragma unroll
            for (int il = 0; il < 4; ++il) {
                const int mbase = m0 + wm * 64 + h * 128 + il * 16 + rowQ;
#pragma unroll
                for (int r = 0; r < 4; ++r) {
                    const float g = aG[h][il][jl][r] + bgv;
                    const float o = aO[h][il][jl][r] + bov;
                    const float hv = g * (1.0f / (1.0f + __expf(-o)));
                    H[(size_t)(mbase + r) * DM + n] = f2bf(hv);
                }
            }
    }
}

// -------- GEMM2: Out = H @ WoutT^T + b; BM=256, BN=128, 4Mx2N waves, no LDS --
// Per wave 64x64 tile; per iter: 4 A-frag + 4 B-frag loads, 16 MFMA.
// ~120 VGPR -> 2 blocks/CU, 4 waves/SIMD.
__global__ __launch_bounds__(512)
void gemm2(const unsigned short* __restrict__ Hlo,
           const unsigned short* __restrict__ Hhi,
           const unsigned short* __restrict__ Bt,
           const float* __restrict__ bout,
           float* __restrict__ Out,
           int row_base) {
    const int tid  = threadIdx.x;
    const int wave = tid >> 6;
    const int lane = tid & 63;
    const int wm = wave & 3;       // 4 M-waves x 64 rows
    const int wn = wave >> 2;      // 2 N-waves x 64 cols

    const int bid = blockIdx.x;
    const int q8  = (int)gridDim.x >> 3;      // 512 or 256 blocks (%8==0)
    const int swz = (bid & 7) * q8 + (bid >> 3);
    const int m0 = row_base + (swz >> 3) * 256;
    const int n0 = (swz & 7) * 128;

    const unsigned short* __restrict__ A =
        (m0 < 8192) ? (Hlo + (size_t)m0 * DM) : (Hhi + (size_t)(m0 - 8192) * DM);

    const int rA = lane & 15;
    const int kq = (lane >> 4) * 8;

    const char* pA = (const char*)A  + ((size_t)(wm * 64 + rA) * DM + kq) * 2;
    const char* pB = (const char*)Bt + ((size_t)(n0 + wn * 64 + rA) * DM + kq) * 2;

    f32x4 acc[4][4];
#pragma unroll
    for (int il = 0; il < 4; ++il)
#pragma unroll
        for (int j = 0; j < 4; ++j) acc[il][j] = (f32x4){0.f, 0.f, 0.f, 0.f};

#pragma unroll 1
    for (int kt = 0; kt < 32; ++kt) {
        const int kb = kt * 64;
        bf16x8 fa[4], fb[4];
#pragma unroll
        for (int il = 0; il < 4; ++il)
            fa[il] = *(const bf16x8*)(pA + (size_t)(il * 16) * 2048 + kb);
#pragma unroll
        for (int jl = 0; jl < 4; ++jl)
            fb[jl] = *(const bf16x8*)(pB + (size_t)(jl * 16) * 2048 + kb);
#pragma unroll
        for (int il = 0; il < 4; ++il)
#pragma unroll
            for (int jl = 0; jl < 4; ++jl)
                acc[il][jl] = __builtin_amdgcn_mfma_f32_16x16x32_bf16(fa[il], fb[jl], acc[il][jl], 0, 0, 0);
    }

    const int colL = lane & 15;
    const int rowQ = (lane >> 4) * 4;
#pragma unroll
    for (int jl = 0; jl < 4; ++jl) {
        const int n = n0 + wn * 64 + jl * 16 + colL;
        const float bv = bout[n];
#pragma unroll
        for (int il = 0; il < 4; ++il) {
            const int mbase = m0 + wm * 64 + il * 16 + rowQ;
#pragma unroll
            for (int r = 0; r < 4; ++r)
                Out[(size_t)(mbase + r) * DM + n] = acc[il][jl][r] + bv;
        }
    }
}

extern "C" void kernel_launch(void* const* d_in, const int* in_sizes, int n_in,
                              void* d_out, int out_size, void* d_ws, size_t ws_size,
                              hipStream_t stream) {
    const float* x     = (const float*)d_in[0];   // [4,4096,1024] fp32
    const float* Wproj = (const float*)d_in[1];   // [1024,3072]   fp32
    const float* bproj = (const float*)d_in[2];   // [3072]        fp32
    const float* Wout  = (const float*)d_in[3];   // [1024,1024]   fp32
    const float* bout  = (const float*)d_in[4];   // [1024]        fp32
    float* out = (float*)d_out;                   // [4,4096,1024] fp32 (64 MB)

    unsigned short* Xb  = (unsigned short*)d_out; // shorts [0,16M): Xbf16 (phases 1-3)
    unsigned short* WgT   = (unsigned short*)d_ws;
    unsigned short* WoT   = WgT + MEG;
    unsigned short* WoutT = WgT + 2 * MEG;
    unsigned short* Hws   = WgT + 3 * MEG;

    const bool big_ws = ws_size >= (size_t)19 * MEG * 2;

    unsigned short* Hlo = big_ws ? Hws : ((unsigned short*)d_out + 16 * MEG);
    unsigned short* Hhi = big_ws ? (Hws + (size_t)8192 * DM) : Hws;

    // 1) Xbf16 (d_out lo) <- fp32 x
    conv_x<<<(MTOT * DM) / (256 * 8), 256, 0, stream>>>(x, Xb);

    // 2) transposed bf16 weight panels -> ws
    transpose_w<<<dim3(32, 32, 3), dim3(32, 8, 1), 0, stream>>>(Wproj, Wout, WgT);

    // 3) H = (X@Wg + bg) * sigmoid(X@Wo + bo), stored split across Hlo/Hhi
    gemm1_fused<<<512, 512, 0, stream>>>(Xb, WgT, WoT, bproj, Hlo, Hhi);

    // 4) out = H @ Wout + b_out
    if (big_ws) {
        gemm2<<<512, 512, 0, stream>>>(Hlo, Hhi, WoutT, bout, out, 0);
    } else {
        // lo half first (reads d_out-hi H, writes d_out-lo out: disjoint),
        // then hi half (reads only ws, overwrites the now-dead H-lo region)
        gemm2<<<256, 512, 0, stream>>>(Hlo, Hhi, WoutT, bout, out, 0);
        gemm2<<<256, 512, 0, stream>>>(Hlo, Hhi, WoutT, bout, out, 8192);
    }
}

// Round 6
// 238.581 us; speedup vs baseline: 1.8057x; 1.8057x over previous
//
#include <hip/hip_runtime.h>
#include <hip/hip_bf16.h>

// B=4, L=4096, D=1024; M = B*L = 16384. ALL I/O IS FP32.
// Live path: h = (x@Wp[:,0:D]) * sigmoid(x@Wp[:,2D:3D]); out = h@W_out + b_out
// Internals: bf16 MFMA, fp32 accumulation.
//
// Round-6:
//  - gemm1: 4 finer phases/K-tile (1 barrier each), same region & vmcnt(4)
//    schedule as the passing round-3/4 kernel.
//  - gemm2: REBUILT at BM=BN=128, 256 thr / 4 waves, 64 KB LDS -> 2 blocks/CU
//    co-resident (round-3 gemm2 ran 1 block/CU and was latency-exposed at
//    ~70us/half; 2-block TLP hides the stall structure, m97-ladder evidence).
// T2 LDS XOR swizzle (slot^=row&7 on 128B rows; linear LDS dest +
// inverse-swizzled global source), T5 setprio, T1 XCD block swizzle.
//
// gemm1 K-tile kt (buf b=kt&1, nb=b^1), phases (1 barrier each):
//   p0: read A-h0(8)+Bg(4); stage kt+1{A2,A3}->nb;   MFMA h0xG (16)
//   p1: read Bo(4);         stage kt+1{Bg1,Bo1}->nb; MFMA h0xO (16)
//   p2: read A-h1(8);       stage kt+2{A0,A1}->b;    MFMA h1xG (16)
//   p3: (no reads)          stage kt+2{Bg0,Bo0}->b;  MFMA h1xO (16); vmcnt(4)
//   boundary invariant: 12 outstanding -> vmcnt(4) drains all of kt+1,
//   leaves kt+2's 4 in flight. Stage targets are >=1 barrier past last read.
//
// gemm2 K-tile (2 phases):
//   p0: read A(8)+B j01(4); stage kt+1{A2,A3,Br1,Br3}->nb; MFMA j01 (16)
//   p1: read B j23(4);      stage kt+2{A0,A1,Br0,Br2}->b;  MFMA j23 (16); vmcnt(4)
//
// Memory plan (ws_size-adaptive, branch constant across calls => graph-safe):
//   ws shorts [0,3M)   : WgT | WoT | WoutT bf16 panels (6 MB)
//   BIG ws (>=38 MB)   : H (16M shorts) entirely at ws+3M; single gemm2 launch.
//   SMALL ws           : H rows 0..8191 -> d_out shorts [16M,24M);
//                        H rows 8192..  -> ws+3M; two sequential gemm2 halves.
//   d_out shorts [0,16M): Xbf16 during phases 1-3, then fp32 out rows 0..8191.

#define MTOT 16384
#define DM   1024
#define MEG  (1024 * 1024)

typedef __bf16 bf16x8 __attribute__((ext_vector_type(8)));
typedef float  f32x4  __attribute__((ext_vector_type(4)));

#define AS1 __attribute__((address_space(1)))
#define AS3 __attribute__((address_space(3)))

static __device__ __forceinline__ void async_load16(const void* g, void* l) {
    __builtin_amdgcn_global_load_lds((const AS1 void*)g, (AS3 void*)l, 16, 0, 0);
}

static __device__ __forceinline__ unsigned short f2bf(float f) {
    __hip_bfloat16 h = __float2bfloat16(f);
    return *(unsigned short*)&h;
}

// ---------------- x (fp32) -> Xbf16 ------------------------------------------
__global__ __launch_bounds__(256)
void conv_x(const float* __restrict__ x, unsigned short* __restrict__ dst) {
    const size_t i = ((size_t)blockIdx.x * 256 + threadIdx.x) * 8;
    const f32x4 a = *(const f32x4*)(x + i);
    const f32x4 b = *(const f32x4*)(x + i + 4);
    __align__(16) unsigned short o[8];
    o[0] = f2bf(a[0]); o[1] = f2bf(a[1]); o[2] = f2bf(a[2]); o[3] = f2bf(a[3]);
    o[4] = f2bf(b[0]); o[5] = f2bf(b[1]); o[6] = f2bf(b[2]); o[7] = f2bf(b[3]);
    *(uint4*)(dst + i) = *(const uint4*)o;
}

// -------- weight transpose+convert: dst[n][k] = bf16(src[k][coff+n]) ---------
__global__ void transpose_w(const float* __restrict__ Wproj, const float* __restrict__ Wout,
                            unsigned short* __restrict__ dst0) {
    __shared__ unsigned short t[32][33];
    const int z = blockIdx.z;
    const float* src;
    unsigned short* dst;
    int ld, coff;
    if (z == 0)      { src = Wproj; ld = 3072; coff = 0;    dst = dst0; }
    else if (z == 1) { src = Wproj; ld = 3072; coff = 2048; dst = dst0 + MEG; }
    else             { src = Wout;  ld = 1024; coff = 0;    dst = dst0 + 2 * MEG; }
    const int k0 = blockIdx.x * 32;
    const int n0 = blockIdx.y * 32;
    const int tx = threadIdx.x, ty = threadIdx.y;
    for (int i = ty; i < 32; i += 8)
        t[i][tx] = f2bf(src[(size_t)(k0 + i) * ld + coff + n0 + tx]);
    __syncthreads();
    for (int i = ty; i < 32; i += 8)
        dst[(size_t)(n0 + i) * DM + k0 + tx] = t[tx][i];
}

// ---------- GEMM1 fused: H = (X@Wg + bg) * sigmoid(X@Wo + bo) ---------------
// 512 thr / 8 waves (2M x 4N); BM=256, BN=128(x2 mats), BK=64, LDS 128 KiB.
__global__ __launch_bounds__(512)
void gemm1_fused(const unsigned short* __restrict__ X,
                 const unsigned short* __restrict__ WgT,
                 const unsigned short* __restrict__ WoT,
                 const float* __restrict__ bproj,
                 unsigned short* __restrict__ Hlo,
                 unsigned short* __restrict__ Hhi) {
    __shared__ __align__(16) unsigned short sA[2][256 * 64];
    __shared__ __align__(16) unsigned short sB[2][256 * 64];

    const int tid  = threadIdx.x;
    const int wave = tid >> 6;
    const int lane = tid & 63;
    const int wm = wave & 1;
    const int wn = wave >> 1;

    // T1: bijective XCD swizzle (512 blocks, %8==0)
    const int bid = blockIdx.x;
    const int swz = (bid & 7) * 64 + (bid >> 3);
    const int m0 = (swz >> 3) * 256;
    const int n0 = (swz & 7) * 128;

    unsigned short* __restrict__ H =
        (m0 < 8192) ? Hlo : (Hhi - (size_t)8192 * DM);

    // swizzled ds_read_b128 lane constants:
    // byte(row,slot) = row*128 + (slot^(row&7))*16, slot = kk*4 + (lane>>4)
    const int rA = lane & 15;
    const int qq = lane >> 4;
    const int r7 = rA & 7;
    const int swq   = ((qq ^ (r7 & 3)) << 4);
    const int k0off = ((rA >> 2) & 1) << 6;
    const int k1off = k0off ^ 64;
    const int ldsA_base = (wm * 64 + rA) * 128 + swq;
    const int ldsB_base = (wn * 16 + rA) * 128 + swq;

    // staging: linear LDS dest (rule #21), inverse-swizzled global source
    const int trow = tid >> 3;
    const int tsw  = (((tid & 7) ^ (trow & 7)) << 4);
    const char* srcA  = (const char*)X   + (size_t)(m0 + trow) * 2048 + tsw;
    const char* srcBg = (const char*)WgT + (size_t)(n0 + trow) * 2048 + tsw;
    const char* srcBo = (const char*)WoT + (size_t)(n0 + trow) * 2048 + tsw;
    char* dA = (char*)&sA[0][0] + tid * 16;
    char* dB = (char*)&sB[0][0] + tid * 16;

#define STA1(b, kt, r)  async_load16(srcA  + (kt) * 128 + (r) * 131072, dA + (b) * 32768 + (r) * 8192)
#define STBG1(b, kt, r) async_load16(srcBg + (kt) * 128 + (r) * 131072, dB + (b) * 32768 + (r) * 8192)
#define STBO1(b, kt, r) async_load16(srcBo + (kt) * 128 + (r) * 131072, dB + (b) * 32768 + (2 + (r)) * 8192)
#define LDA1(dst, bb, h, il, kof) dst = *(const bf16x8*)((const char*)sA + (bb) * 32768 + ldsA_base + (h) * 16384 + (il) * 2048 + (kof))
#define LDB1(dst, bb, mat, j, kof) dst = *(const bf16x8*)((const char*)sB + (bb) * 32768 + ldsB_base + (mat) * 16384 + (j) * 8192 + (kof))

    f32x4 aG[2][4][2], aO[2][4][2];
    bf16x8 fa[4][2], fbg[2][2], fbo[2][2];

    // prologue: tile0 complete (8 loads), then tile1's {A0,A1,Bg0,Bo0}
    STA1(0, 0, 0); STA1(0, 0, 1); STA1(0, 0, 2); STA1(0, 0, 3);
    STBG1(0, 0, 0); STBG1(0, 0, 1); STBO1(0, 0, 0); STBO1(0, 0, 1);
    STA1(1, 1, 0); STA1(1, 1, 1); STBG1(1, 1, 0); STBO1(1, 1, 0);

#pragma unroll
    for (int h = 0; h < 2; ++h)
#pragma unroll
        for (int il = 0; il < 4; ++il)
#pragma unroll
            for (int jl = 0; jl < 2; ++jl) {
                aG[h][il][jl] = (f32x4){0.f, 0.f, 0.f, 0.f};
                aO[h][il][jl] = (f32x4){0.f, 0.f, 0.f, 0.f};
            }

    asm volatile("s_waitcnt vmcnt(4)" ::: "memory");   // tile0 landed
    __builtin_amdgcn_s_barrier();

// K-outer: 8 independent MFMAs per kk within a 16-MFMA quadrant.
#define MMG1(H_) do { \
    _Pragma("unroll") \
    for (int kk = 0; kk < 2; ++kk) \
        _Pragma("unroll") \
        for (int il = 0; il < 4; ++il) \
            _Pragma("unroll") \
            for (int jl = 0; jl < 2; ++jl) \
                aG[H_][il][jl] = __builtin_amdgcn_mfma_f32_16x16x32_bf16(fa[il][kk], fbg[jl][kk], aG[H_][il][jl], 0, 0, 0); \
    } while (0)
#define MMO1(H_) do { \
    _Pragma("unroll") \
    for (int kk = 0; kk < 2; ++kk) \
        _Pragma("unroll") \
        for (int il = 0; il < 4; ++il) \
            _Pragma("unroll") \
            for (int jl = 0; jl < 2; ++jl) \
                aO[H_][il][jl] = __builtin_amdgcn_mfma_f32_16x16x32_bf16(fa[il][kk], fbo[jl][kk], aO[H_][il][jl], 0, 0, 0); \
    } while (0)

#define LGKM_SGB() \
    asm volatile("s_waitcnt lgkmcnt(0)" ::: "memory"); \
    __builtin_amdgcn_sched_barrier(0)

#define TILE1(kt, b, nb) do { \
    /* p0: read A-h0 + Bg; stage kt+1 {A2,A3} -> nb */ \
    _Pragma("unroll") \
    for (int il = 0; il < 4; ++il) { LDA1(fa[il][0], b, 0, il, k0off); LDA1(fa[il][1], b, 0, il, k1off); } \
    _Pragma("unroll") \
    for (int jl = 0; jl < 2; ++jl) { LDB1(fbg[jl][0], b, 0, jl, k0off); LDB1(fbg[jl][1], b, 0, jl, k1off); } \
    if ((kt) < 15) { STA1(nb, (kt) + 1, 2); STA1(nb, (kt) + 1, 3); } \
    LGKM_SGB(); \
    __builtin_amdgcn_s_setprio(1); MMG1(0); __builtin_amdgcn_s_setprio(0); \
    __builtin_amdgcn_s_barrier(); \
    /* p1: read Bo; stage kt+1 {Bg1,Bo1} -> nb */ \
    _Pragma("unroll") \
    for (int jl = 0; jl < 2; ++jl) { LDB1(fbo[jl][0], b, 1, jl, k0off); LDB1(fbo[jl][1], b, 1, jl, k1off); } \
    if ((kt) < 15) { STBG1(nb, (kt) + 1, 1); STBO1(nb, (kt) + 1, 1); } \
    LGKM_SGB(); \
    __builtin_amdgcn_s_setprio(1); MMO1(0); __builtin_amdgcn_s_setprio(0); \
    __builtin_amdgcn_s_barrier(); \
    /* p2: read A-h1; stage kt+2 {A0,A1} -> b (A-h0 of b dead since p0) */ \
    _Pragma("unroll") \
    for (int il = 0; il < 4; ++il) { LDA1(fa[il][0], b, 1, il, k0off); LDA1(fa[il][1], b, 1, il, k1off); } \
    if ((kt) < 14) { STA1(b, (kt) + 2, 0); STA1(b, (kt) + 2, 1); } \
    LGKM_SGB(); \
    __builtin_amdgcn_s_setprio(1); MMG1(1); __builtin_amdgcn_s_setprio(0); \
    __builtin_amdgcn_s_barrier(); \
    /* p3: no reads; stage kt+2 {Bg0,Bo0} -> b (Bg dead p1+, Bo dead p2+) */ \
    if ((kt) < 14) { STBG1(b, (kt) + 2, 0); STBO1(b, (kt) + 2, 0); } \
    __builtin_amdgcn_s_setprio(1); MMO1(1); __builtin_amdgcn_s_setprio(0); \
    if ((kt) < 14) { asm volatile("s_waitcnt vmcnt(4)" ::: "memory"); } \
    else           { asm volatile("s_waitcnt vmcnt(0)" ::: "memory"); } \
    __builtin_amdgcn_s_barrier(); \
} while (0)

#pragma unroll 1
    for (int kt2 = 0; kt2 < 16; kt2 += 2) {
        TILE1(kt2, 0, 1);
        TILE1(kt2 + 1, 1, 0);
    }
#undef TILE1
#undef MMG1
#undef MMO1
#undef STA1
#undef STBG1
#undef STBO1
#undef LDA1
#undef LDB1

    const int colL = lane & 15;
    const int rowQ = (lane >> 4) * 4;
#pragma unroll
    for (int jl = 0; jl < 2; ++jl) {
        const int n = n0 + wn * 16 + jl * 64 + colL;
        const float bgv = bproj[n];
        const float bov = bproj[2048 + n];
#pragma unroll
        for (int h = 0; h < 2; ++h)
#pragma unroll
            for (int il = 0; il < 4; ++il) {
                const int mbase = m0 + wm * 64 + h * 128 + il * 16 + rowQ;
#pragma unroll
                for (int r = 0; r < 4; ++r) {
                    const float g = aG[h][il][jl][r] + bgv;
                    const float o = aO[h][il][jl][r] + bov;
                    const float hv = g * (1.0f / (1.0f + __expf(-o)));
                    H[(size_t)(mbase + r) * DM + n] = f2bf(hv);
                }
            }
    }
}

// -------- GEMM2: Out = H @ WoutT^T + b; BM=BN=128, 256 thr, 2 blocks/CU ------
// 4 waves (2M x 2N), per-wave 64x64 out; LDS 64 KiB (2buf x (A128+B128) x 64).
__global__ __launch_bounds__(256)
void gemm2(const unsigned short* __restrict__ Hlo,
           const unsigned short* __restrict__ Hhi,
           const unsigned short* __restrict__ Bt,
           const float* __restrict__ bout,
           float* __restrict__ Out,
           int row_base) {
    __shared__ __align__(16) unsigned short sA[2][128 * 64];
    __shared__ __align__(16) unsigned short sB[2][128 * 64];

    const int tid  = threadIdx.x;
    const int wave = tid >> 6;
    const int lane = tid & 63;
    const int wm = wave & 1;       // 2 M-waves x 64 rows
    const int wn = wave >> 1;      // 2 N-waves x 64 cols

    const int bid = blockIdx.x;
    const int q8  = (int)gridDim.x >> 3;      // 1024 or 512 blocks (%8==0)
    const int swz = (bid & 7) * q8 + (bid >> 3);
    const int m0 = row_base + (swz >> 3) * 128;
    const int n0 = (swz & 7) * 128;

    const unsigned short* __restrict__ A =
        (m0 < 8192) ? (Hlo + (size_t)m0 * DM) : (Hhi + (size_t)(m0 - 8192) * DM);

    const int rA = lane & 15;
    const int qq = lane >> 4;
    const int r7 = rA & 7;
    const int swq   = ((qq ^ (r7 & 3)) << 4);
    const int k0off = ((rA >> 2) & 1) << 6;
    const int k1off = k0off ^ 64;
    const int ldsA_base = (wm * 64 + rA) * 128 + swq;
    const int ldsB_base = (wn * 64 + rA) * 128 + swq;

    // staging: 256 threads; region = 32 rows (4 KiB LDS, 64 KiB global span)
    const int trow = tid >> 3;                // 0..31
    const int tsw  = (((tid & 7) ^ (trow & 7)) << 4);
    const char* srcA = (const char*)A  + (size_t)trow * 2048 + tsw;
    const char* srcB = (const char*)Bt + (size_t)(n0 + trow) * 2048 + tsw;
    char* dA = (char*)&sA[0][0] + tid * 16;
    char* dB = (char*)&sB[0][0] + tid * 16;

#define STA2(b, kt, r) async_load16(srcA + (kt) * 128 + (r) * 65536, dA + (b) * 16384 + (r) * 4096)
#define STB2(b, kt, r) async_load16(srcB + (kt) * 128 + (r) * 65536, dB + (b) * 16384 + (r) * 4096)
#define LDA2(dst, bb, il, kof) dst = *(const bf16x8*)((const char*)sA + (bb) * 16384 + ldsA_base + (il) * 2048 + (kof))
#define LDB2(dst, bb, jl, kof) dst = *(const bf16x8*)((const char*)sB + (bb) * 16384 + ldsB_base + (jl) * 2048 + (kof))

    f32x4 acc[4][4];
    bf16x8 fa[4][2], fb[4][2];

    // prologue: tile0 all 8 regions, then tile1's {A0,A1,Br0,Br2}
    STA2(0, 0, 0); STA2(0, 0, 1); STA2(0, 0, 2); STA2(0, 0, 3);
    STB2(0, 0, 0); STB2(0, 0, 1); STB2(0, 0, 2); STB2(0, 0, 3);
    STA2(1, 1, 0); STA2(1, 1, 1); STB2(1, 1, 0); STB2(1, 1, 2);

#pragma unroll
    for (int il = 0; il < 4; ++il)
#pragma unroll
        for (int j = 0; j < 4; ++j) acc[il][j] = (f32x4){0.f, 0.f, 0.f, 0.f};

    asm volatile("s_waitcnt vmcnt(4)" ::: "memory");   // tile0 landed
    __builtin_amdgcn_s_barrier();

#define MM2(JB) do { \
    _Pragma("unroll") \
    for (int kk = 0; kk < 2; ++kk) \
        _Pragma("unroll") \
        for (int il = 0; il < 4; ++il) { \
            acc[il][JB]     = __builtin_amdgcn_mfma_f32_16x16x32_bf16(fa[il][kk], fb[JB][kk],     acc[il][JB],     0, 0, 0); \
            acc[il][JB + 1] = __builtin_amdgcn_mfma_f32_16x16x32_bf16(fa[il][kk], fb[JB + 1][kk], acc[il][JB + 1], 0, 0, 0); \
        } } while (0)

// B read regions: j01 touches Br0(w0)/Br2(w1); j23 touches Br1(w0)/Br3(w1).
#define TILE2(kt, b, nb) do { \
    /* p0: read A(8)+B j01(4); stage kt+1 {A2,A3,Br1,Br3} -> nb */ \
    _Pragma("unroll") \
    for (int il = 0; il < 4; ++il) { LDA2(fa[il][0], b, il, k0off); LDA2(fa[il][1], b, il, k1off); } \
    _Pragma("unroll") \
    for (int jl = 0; jl < 2; ++jl) { LDB2(fb[jl][0], b, jl, k0off); LDB2(fb[jl][1], b, jl, k1off); } \
    if ((kt) < 15) { STA2(nb, (kt) + 1, 2); STA2(nb, (kt) + 1, 3); STB2(nb, (kt) + 1, 1); STB2(nb, (kt) + 1, 3); } \
    asm volatile("s_waitcnt lgkmcnt(0)" ::: "memory"); \
    __builtin_amdgcn_sched_barrier(0); \
    __builtin_amdgcn_s_setprio(1); MM2(0); __builtin_amdgcn_s_setprio(0); \
    __builtin_amdgcn_s_barrier(); \
    /* p1: read B j23(4); stage kt+2 {A0,A1,Br0,Br2} -> b (dead since p0) */ \
    _Pragma("unroll") \
    for (int jl = 2; jl < 4; ++jl) { LDB2(fb[jl][0], b, jl, k0off); LDB2(fb[jl][1], b, jl, k1off); } \
    if ((kt) < 14) { STA2(b, (kt) + 2, 0); STA2(b, (kt) + 2, 1); STB2(b, (kt) + 2, 0); STB2(b, (kt) + 2, 2); } \
    asm volatile("s_waitcnt lgkmcnt(0)" ::: "memory"); \
    __builtin_amdgcn_sched_barrier(0); \
    __builtin_amdgcn_s_setprio(1); MM2(2); __builtin_amdgcn_s_setprio(0); \
    if ((kt) < 14) { asm volatile("s_waitcnt vmcnt(4)" ::: "memory"); } \
    else           { asm volatile("s_waitcnt vmcnt(0)" ::: "memory"); } \
    __builtin_amdgcn_s_barrier(); \
} while (0)

#pragma unroll 1
    for (int kt2 = 0; kt2 < 16; kt2 += 2) {
        TILE2(kt2, 0, 1);
        TILE2(kt2 + 1, 1, 0);
    }
#undef TILE2
#undef MM2
#undef STA2
#undef STB2
#undef LDA2
#undef LDB2

    const int colL = lane & 15;
    const int rowQ = (lane >> 4) * 4;
#pragma unroll
    for (int jl = 0; jl < 4; ++jl) {
        const int n = n0 + wn * 64 + jl * 16 + colL;
        const float bv = bout[n];
#pragma unroll
        for (int il = 0; il < 4; ++il) {
            const int mbase = m0 + wm * 64 + il * 16 + rowQ;
#pragma unroll
            for (int r = 0; r < 4; ++r)
                Out[(size_t)(mbase + r) * DM + n] = acc[il][jl][r] + bv;
        }
    }
}

extern "C" void kernel_launch(void* const* d_in, const int* in_sizes, int n_in,
                              void* d_out, int out_size, void* d_ws, size_t ws_size,
                              hipStream_t stream) {
    const float* x     = (const float*)d_in[0];   // [4,4096,1024] fp32
    const float* Wproj = (const float*)d_in[1];   // [1024,3072]   fp32
    const float* bproj = (const float*)d_in[2];   // [3072]        fp32
    const float* Wout  = (const float*)d_in[3];   // [1024,1024]   fp32
    const float* bout  = (const float*)d_in[4];   // [1024]        fp32
    float* out = (float*)d_out;                   // [4,4096,1024] fp32 (64 MB)

    unsigned short* Xb  = (unsigned short*)d_out; // shorts [0,16M): Xbf16 (phases 1-3)
    unsigned short* WgT   = (unsigned short*)d_ws;
    unsigned short* WoT   = WgT + MEG;
    unsigned short* WoutT = WgT + 2 * MEG;
    unsigned short* Hws   = WgT + 3 * MEG;

    const bool big_ws = ws_size >= (size_t)19 * MEG * 2;

    unsigned short* Hlo = big_ws ? Hws : ((unsigned short*)d_out + 16 * MEG);
    unsigned short* Hhi = big_ws ? (Hws + (size_t)8192 * DM) : Hws;

    // 1) Xbf16 (d_out lo) <- fp32 x
    conv_x<<<(MTOT * DM) / (256 * 8), 256, 0, stream>>>(x, Xb);

    // 2) transposed bf16 weight panels -> ws
    transpose_w<<<dim3(32, 32, 3), dim3(32, 8, 1), 0, stream>>>(Wproj, Wout, WgT);

    // 3) H = (X@Wg + bg) * sigmoid(X@Wo + bo), stored split across Hlo/Hhi
    gemm1_fused<<<512, 512, 0, stream>>>(Xb, WgT, WoT, bproj, Hlo, Hhi);

    // 4) out = H @ Wout + b_out (128x128 tiles, 2 blocks/CU)
    if (big_ws) {
        gemm2<<<1024, 256, 0, stream>>>(Hlo, Hhi, WoutT, bout, out, 0);
    } else {
        // lo half first (reads d_out-hi H, writes d_out-lo out: disjoint),
        // then hi half (reads only ws, overwrites the now-dead H-lo region)
        gemm2<<<512, 256, 0, stream>>>(Hlo, Hhi, WoutT, bout, out, 0);
        gemm2<<<512, 256, 0, stream>>>(Hlo, Hhi, WoutT, bout, out, 8192);
    }
}

// Round 7
// 236.645 us; speedup vs baseline: 1.8204x; 1.0082x over previous
//
#include <hip/hip_runtime.h>
#include <hip/hip_bf16.h>

// B=4, L=4096, D=1024; M = B*L = 16384. ALL I/O IS FP32.
// Live path: h = (x@Wp[:,0:D]) * sigmoid(x@Wp[:,2D:3D]); out = h@W_out + b_out
// Internals: bf16 MFMA, fp32 accumulation.
//
// Round-7 change (ONLY): the lgkmcnt(0)+sched_barrier(0) wall moved from
// BEFORE each MFMA cluster to the END of each phase. Round 2-6 pinned
// reads->drain->MFMA (m141's order-pinning mistake): LDS read burst
// (192 b128 x ~12cyc = 2304 cyc/tile) serialized against MFMA burst
// (512 MFMA / 0.206 per cyc = 2483 cyc/tile) -> 5550 cyc/tile = 74us,
// MfmaUtil 37% == 2483/5550. Now the compiler free-schedules reads/MFMA
// inside a phase with its own counted lgkmcnt (plain loads, def-use
// visible -- rule 18 applies only to asm ds_reads). Phase-end wall keeps
// every round-6 safety invariant: each wave's reads are consumed (lgkm
// drained) before the barrier, so stages into those regions issued in
// later phases cannot race; counted vmcnt unchanged.
//
// gemm1 K-tile kt (buf b=kt&1, nb=b^1), 4 phases, 1 barrier each:
//   p0: read A-h0(8)+Bg(4); stage kt+1{A2,A3}->nb;   MFMA h0xG (16)
//   p1: read Bo(4);         stage kt+1{Bg1,Bo1}->nb; MFMA h0xO (16)
//   p2: read A-h1(8);       stage kt+2{A0,A1}->b;    MFMA h1xG (16)
//   p3: (no reads)          stage kt+2{Bg0,Bo0}->b;  MFMA h1xO (16); vmcnt(4)
// gemm2 (128x128, 256thr, 2 blocks/CU) K-tile, 2 phases:
//   p0: read A(8)+B j01(4); stage kt+1{A2,A3,Br1,Br3}->nb; MFMA j01 (16)
//   p1: read B j23(4);      stage kt+2{A0,A1,Br0,Br2}->b;  MFMA j23 (16); vmcnt(4)
// T2 LDS XOR swizzle (slot^=row&7 on 128B rows; linear LDS dest +
// inverse-swizzled global source), T1 XCD block swizzle.
//
// Memory plan (ws_size-adaptive, branch constant across calls => graph-safe):
//   ws shorts [0,3M)   : WgT | WoT | WoutT bf16 panels (6 MB)
//   BIG ws (>=38 MB)   : H (16M shorts) entirely at ws+3M; single gemm2 launch.
//   SMALL ws           : H rows 0..8191 -> d_out shorts [16M,24M);
//                        H rows 8192..  -> ws+3M; two sequential gemm2 halves.
//   d_out shorts [0,16M): Xbf16 during phases 1-3, then fp32 out rows 0..8191.

#define MTOT 16384
#define DM   1024
#define MEG  (1024 * 1024)

typedef __bf16 bf16x8 __attribute__((ext_vector_type(8)));
typedef float  f32x4  __attribute__((ext_vector_type(4)));

#define AS1 __attribute__((address_space(1)))
#define AS3 __attribute__((address_space(3)))

static __device__ __forceinline__ void async_load16(const void* g, void* l) {
    __builtin_amdgcn_global_load_lds((const AS1 void*)g, (AS3 void*)l, 16, 0, 0);
}

static __device__ __forceinline__ unsigned short f2bf(float f) {
    __hip_bfloat16 h = __float2bfloat16(f);
    return *(unsigned short*)&h;
}

// ---------------- x (fp32) -> Xbf16 ------------------------------------------
__global__ __launch_bounds__(256)
void conv_x(const float* __restrict__ x, unsigned short* __restrict__ dst) {
    const size_t i = ((size_t)blockIdx.x * 256 + threadIdx.x) * 8;
    const f32x4 a = *(const f32x4*)(x + i);
    const f32x4 b = *(const f32x4*)(x + i + 4);
    __align__(16) unsigned short o[8];
    o[0] = f2bf(a[0]); o[1] = f2bf(a[1]); o[2] = f2bf(a[2]); o[3] = f2bf(a[3]);
    o[4] = f2bf(b[0]); o[5] = f2bf(b[1]); o[6] = f2bf(b[2]); o[7] = f2bf(b[3]);
    *(uint4*)(dst + i) = *(const uint4*)o;
}

// -------- weight transpose+convert: dst[n][k] = bf16(src[k][coff+n]) ---------
__global__ void transpose_w(const float* __restrict__ Wproj, const float* __restrict__ Wout,
                            unsigned short* __restrict__ dst0) {
    __shared__ unsigned short t[32][33];
    const int z = blockIdx.z;
    const float* src;
    unsigned short* dst;
    int ld, coff;
    if (z == 0)      { src = Wproj; ld = 3072; coff = 0;    dst = dst0; }
    else if (z == 1) { src = Wproj; ld = 3072; coff = 2048; dst = dst0 + MEG; }
    else             { src = Wout;  ld = 1024; coff = 0;    dst = dst0 + 2 * MEG; }
    const int k0 = blockIdx.x * 32;
    const int n0 = blockIdx.y * 32;
    const int tx = threadIdx.x, ty = threadIdx.y;
    for (int i = ty; i < 32; i += 8)
        t[i][tx] = f2bf(src[(size_t)(k0 + i) * ld + coff + n0 + tx]);
    __syncthreads();
    for (int i = ty; i < 32; i += 8)
        dst[(size_t)(n0 + i) * DM + k0 + tx] = t[tx][i];
}

// ---------- GEMM1 fused: H = (X@Wg + bg) * sigmoid(X@Wo + bo) ---------------
// 512 thr / 8 waves (2M x 4N); BM=256, BN=128(x2 mats), BK=64, LDS 128 KiB.
__global__ __launch_bounds__(512)
void gemm1_fused(const unsigned short* __restrict__ X,
                 const unsigned short* __restrict__ WgT,
                 const unsigned short* __restrict__ WoT,
                 const float* __restrict__ bproj,
                 unsigned short* __restrict__ Hlo,
                 unsigned short* __restrict__ Hhi) {
    __shared__ __align__(16) unsigned short sA[2][256 * 64];
    __shared__ __align__(16) unsigned short sB[2][256 * 64];

    const int tid  = threadIdx.x;
    const int wave = tid >> 6;
    const int lane = tid & 63;
    const int wm = wave & 1;
    const int wn = wave >> 1;

    // T1: bijective XCD swizzle (512 blocks, %8==0)
    const int bid = blockIdx.x;
    const int swz = (bid & 7) * 64 + (bid >> 3);
    const int m0 = (swz >> 3) * 256;
    const int n0 = (swz & 7) * 128;

    unsigned short* __restrict__ H =
        (m0 < 8192) ? Hlo : (Hhi - (size_t)8192 * DM);

    // swizzled ds_read_b128 lane constants:
    // byte(row,slot) = row*128 + (slot^(row&7))*16, slot = kk*4 + (lane>>4)
    const int rA = lane & 15;
    const int qq = lane >> 4;
    const int r7 = rA & 7;
    const int swq   = ((qq ^ (r7 & 3)) << 4);
    const int k0off = ((rA >> 2) & 1) << 6;
    const int k1off = k0off ^ 64;
    const int ldsA_base = (wm * 64 + rA) * 128 + swq;
    const int ldsB_base = (wn * 16 + rA) * 128 + swq;

    // staging: linear LDS dest (rule #21), inverse-swizzled global source
    const int trow = tid >> 3;
    const int tsw  = (((tid & 7) ^ (trow & 7)) << 4);
    const char* srcA  = (const char*)X   + (size_t)(m0 + trow) * 2048 + tsw;
    const char* srcBg = (const char*)WgT + (size_t)(n0 + trow) * 2048 + tsw;
    const char* srcBo = (const char*)WoT + (size_t)(n0 + trow) * 2048 + tsw;
    char* dA = (char*)&sA[0][0] + tid * 16;
    char* dB = (char*)&sB[0][0] + tid * 16;

#define STA1(b, kt, r)  async_load16(srcA  + (kt) * 128 + (r) * 131072, dA + (b) * 32768 + (r) * 8192)
#define STBG1(b, kt, r) async_load16(srcBg + (kt) * 128 + (r) * 131072, dB + (b) * 32768 + (r) * 8192)
#define STBO1(b, kt, r) async_load16(srcBo + (kt) * 128 + (r) * 131072, dB + (b) * 32768 + (2 + (r)) * 8192)
#define LDA1(dst, bb, h, il, kof) dst = *(const bf16x8*)((const char*)sA + (bb) * 32768 + ldsA_base + (h) * 16384 + (il) * 2048 + (kof))
#define LDB1(dst, bb, mat, j, kof) dst = *(const bf16x8*)((const char*)sB + (bb) * 32768 + ldsB_base + (mat) * 16384 + (j) * 8192 + (kof))

    f32x4 aG[2][4][2], aO[2][4][2];
    bf16x8 fa[4][2], fbg[2][2], fbo[2][2];

    // prologue: tile0 complete (8 loads), then tile1's {A0,A1,Bg0,Bo0}
    STA1(0, 0, 0); STA1(0, 0, 1); STA1(0, 0, 2); STA1(0, 0, 3);
    STBG1(0, 0, 0); STBG1(0, 0, 1); STBO1(0, 0, 0); STBO1(0, 0, 1);
    STA1(1, 1, 0); STA1(1, 1, 1); STBG1(1, 1, 0); STBO1(1, 1, 0);

#pragma unroll
    for (int h = 0; h < 2; ++h)
#pragma unroll
        for (int il = 0; il < 4; ++il)
#pragma unroll
            for (int jl = 0; jl < 2; ++jl) {
                aG[h][il][jl] = (f32x4){0.f, 0.f, 0.f, 0.f};
                aO[h][il][jl] = (f32x4){0.f, 0.f, 0.f, 0.f};
            }

    asm volatile("s_waitcnt vmcnt(4)" ::: "memory");   // tile0 landed
    __builtin_amdgcn_s_barrier();

// K-outer: 8 independent MFMAs per kk within a 16-MFMA quadrant.
#define MMG1(H_) do { \
    _Pragma("unroll") \
    for (int kk = 0; kk < 2; ++kk) \
        _Pragma("unroll") \
        for (int il = 0; il < 4; ++il) \
            _Pragma("unroll") \
            for (int jl = 0; jl < 2; ++jl) \
                aG[H_][il][jl] = __builtin_amdgcn_mfma_f32_16x16x32_bf16(fa[il][kk], fbg[jl][kk], aG[H_][il][jl], 0, 0, 0); \
    } while (0)
#define MMO1(H_) do { \
    _Pragma("unroll") \
    for (int kk = 0; kk < 2; ++kk) \
        _Pragma("unroll") \
        for (int il = 0; il < 4; ++il) \
            _Pragma("unroll") \
            for (int jl = 0; jl < 2; ++jl) \
                aO[H_][il][jl] = __builtin_amdgcn_mfma_f32_16x16x32_bf16(fa[il][kk], fbo[jl][kk], aO[H_][il][jl], 0, 0, 0); \
    } while (0)

// Phase-end wall: each wave's reads are fully drained (consumption already
// did it; this is ~free), then a hard scheduler wall so nothing migrates
// across the barrier. Inside the phase, the compiler interleaves
// reads/stages/MFMA with its own counted lgkmcnt.
#define PHASE_END() \
    asm volatile("s_waitcnt lgkmcnt(0)" ::: "memory"); \
    __builtin_amdgcn_sched_barrier(0); \
    __builtin_amdgcn_s_barrier()

#define TILE1(kt, b, nb) do { \
    /* p0: read A-h0 + Bg; stage kt+1 {A2,A3} -> nb; MFMA h0xG */ \
    _Pragma("unroll") \
    for (int il = 0; il < 4; ++il) { LDA1(fa[il][0], b, 0, il, k0off); LDA1(fa[il][1], b, 0, il, k1off); } \
    _Pragma("unroll") \
    for (int jl = 0; jl < 2; ++jl) { LDB1(fbg[jl][0], b, 0, jl, k0off); LDB1(fbg[jl][1], b, 0, jl, k1off); } \
    if ((kt) < 15) { STA1(nb, (kt) + 1, 2); STA1(nb, (kt) + 1, 3); } \
    MMG1(0); \
    PHASE_END(); \
    /* p1: read Bo; stage kt+1 {Bg1,Bo1} -> nb; MFMA h0xO */ \
    _Pragma("unroll") \
    for (int jl = 0; jl < 2; ++jl) { LDB1(fbo[jl][0], b, 1, jl, k0off); LDB1(fbo[jl][1], b, 1, jl, k1off); } \
    if ((kt) < 15) { STBG1(nb, (kt) + 1, 1); STBO1(nb, (kt) + 1, 1); } \
    MMO1(0); \
    PHASE_END(); \
    /* p2: read A-h1; stage kt+2 {A0,A1} -> b; MFMA h1xG */ \
    _Pragma("unroll") \
    for (int il = 0; il < 4; ++il) { LDA1(fa[il][0], b, 1, il, k0off); LDA1(fa[il][1], b, 1, il, k1off); } \
    if ((kt) < 14) { STA1(b, (kt) + 2, 0); STA1(b, (kt) + 2, 1); } \
    MMG1(1); \
    PHASE_END(); \
    /* p3: no reads; stage kt+2 {Bg0,Bo0} -> b; MFMA h1xO; counted vmcnt */ \
    if ((kt) < 14) { STBG1(b, (kt) + 2, 0); STBO1(b, (kt) + 2, 0); } \
    MMO1(1); \
    asm volatile("s_waitcnt lgkmcnt(0)" ::: "memory"); \
    __builtin_amdgcn_sched_barrier(0); \
    if ((kt) < 14) { asm volatile("s_waitcnt vmcnt(4)" ::: "memory"); } \
    else           { asm volatile("s_waitcnt vmcnt(0)" ::: "memory"); } \
    __builtin_amdgcn_s_barrier(); \
} while (0)

#pragma unroll 1
    for (int kt2 = 0; kt2 < 16; kt2 += 2) {
        TILE1(kt2, 0, 1);
        TILE1(kt2 + 1, 1, 0);
    }
#undef TILE1
#undef MMG1
#undef MMO1
#undef STA1
#undef STBG1
#undef STBO1
#undef LDA1
#undef LDB1

    const int colL = lane & 15;
    const int rowQ = (lane >> 4) * 4;
#pragma unroll
    for (int jl = 0; jl < 2; ++jl) {
        const int n = n0 + wn * 16 + jl * 64 + colL;
        const float bgv = bproj[n];
        const float bov = bproj[2048 + n];
#pragma unroll
        for (int h = 0; h < 2; ++h)
#pragma unroll
            for (int il = 0; il < 4; ++il) {
                const int mbase = m0 + wm * 64 + h * 128 + il * 16 + rowQ;
#pragma unroll
                for (int r = 0; r < 4; ++r) {
                    const float g = aG[h][il][jl][r] + bgv;
                    const float o = aO[h][il][jl][r] + bov;
                    const float hv = g * (1.0f / (1.0f + __expf(-o)));
                    H[(size_t)(mbase + r) * DM + n] = f2bf(hv);
                }
            }
    }
}

// -------- GEMM2: Out = H @ WoutT^T + b; BM=BN=128, 256 thr, 2 blocks/CU ------
// 4 waves (2M x 2N), per-wave 64x64 out; LDS 64 KiB (2buf x (A128+B128) x 64).
__global__ __launch_bounds__(256)
void gemm2(const unsigned short* __restrict__ Hlo,
           const unsigned short* __restrict__ Hhi,
           const unsigned short* __restrict__ Bt,
           const float* __restrict__ bout,
           float* __restrict__ Out,
           int row_base) {
    __shared__ __align__(16) unsigned short sA[2][128 * 64];
    __shared__ __align__(16) unsigned short sB[2][128 * 64];

    const int tid  = threadIdx.x;
    const int wave = tid >> 6;
    const int lane = tid & 63;
    const int wm = wave & 1;       // 2 M-waves x 64 rows
    const int wn = wave >> 1;      // 2 N-waves x 64 cols

    const int bid = blockIdx.x;
    const int q8  = (int)gridDim.x >> 3;      // 1024 or 512 blocks (%8==0)
    const int swz = (bid & 7) * q8 + (bid >> 3);
    const int m0 = row_base + (swz >> 3) * 128;
    const int n0 = (swz & 7) * 128;

    const unsigned short* __restrict__ A =
        (m0 < 8192) ? (Hlo + (size_t)m0 * DM) : (Hhi + (size_t)(m0 - 8192) * DM);

    const int rA = lane & 15;
    const int qq = lane >> 4;
    const int r7 = rA & 7;
    const int swq   = ((qq ^ (r7 & 3)) << 4);
    const int k0off = ((rA >> 2) & 1) << 6;
    const int k1off = k0off ^ 64;
    const int ldsA_base = (wm * 64 + rA) * 128 + swq;
    const int ldsB_base = (wn * 64 + rA) * 128 + swq;

    // staging: 256 threads; region = 32 rows (4 KiB LDS, 64 KiB global span)
    const int trow = tid >> 3;                // 0..31
    const int tsw  = (((tid & 7) ^ (trow & 7)) << 4);
    const char* srcA = (const char*)A  + (size_t)trow * 2048 + tsw;
    const char* srcB = (const char*)Bt + (size_t)(n0 + trow) * 2048 + tsw;
    char* dA = (char*)&sA[0][0] + tid * 16;
    char* dB = (char*)&sB[0][0] + tid * 16;

#define STA2(b, kt, r) async_load16(srcA + (kt) * 128 + (r) * 65536, dA + (b) * 16384 + (r) * 4096)
#define STB2(b, kt, r) async_load16(srcB + (kt) * 128 + (r) * 65536, dB + (b) * 16384 + (r) * 4096)
#define LDA2(dst, bb, il, kof) dst = *(const bf16x8*)((const char*)sA + (bb) * 16384 + ldsA_base + (il) * 2048 + (kof))
#define LDB2(dst, bb, jl, kof) dst = *(const bf16x8*)((const char*)sB + (bb) * 16384 + ldsB_base + (jl) * 2048 + (kof))

    f32x4 acc[4][4];
    bf16x8 fa[4][2], fb[4][2];

    // prologue: tile0 all 8 regions, then tile1's {A0,A1,Br0,Br2}
    STA2(0, 0, 0); STA2(0, 0, 1); STA2(0, 0, 2); STA2(0, 0, 3);
    STB2(0, 0, 0); STB2(0, 0, 1); STB2(0, 0, 2); STB2(0, 0, 3);
    STA2(1, 1, 0); STA2(1, 1, 1); STB2(1, 1, 0); STB2(1, 1, 2);

#pragma unroll
    for (int il = 0; il < 4; ++il)
#pragma unroll
        for (int j = 0; j < 4; ++j) acc[il][j] = (f32x4){0.f, 0.f, 0.f, 0.f};

    asm volatile("s_waitcnt vmcnt(4)" ::: "memory");   // tile0 landed
    __builtin_amdgcn_s_barrier();

#define MM2(JB) do { \
    _Pragma("unroll") \
    for (int kk = 0; kk < 2; ++kk) \
        _Pragma("unroll") \
        for (int il = 0; il < 4; ++il) { \
            acc[il][JB]     = __builtin_amdgcn_mfma_f32_16x16x32_bf16(fa[il][kk], fb[JB][kk],     acc[il][JB],     0, 0, 0); \
            acc[il][JB + 1] = __builtin_amdgcn_mfma_f32_16x16x32_bf16(fa[il][kk], fb[JB + 1][kk], acc[il][JB + 1], 0, 0, 0); \
        } } while (0)

// B read regions: j01 touches Br0(w0)/Br2(w1); j23 touches Br1(w0)/Br3(w1).
#define TILE2(kt, b, nb) do { \
    /* p0: read A(8)+B j01(4); stage kt+1 {A2,A3,Br1,Br3} -> nb; MFMA j01 */ \
    _Pragma("unroll") \
    for (int il = 0; il < 4; ++il) { LDA2(fa[il][0], b, il, k0off); LDA2(fa[il][1], b, il, k1off); } \
    _Pragma("unroll") \
    for (int jl = 0; jl < 2; ++jl) { LDB2(fb[jl][0], b, jl, k0off); LDB2(fb[jl][1], b, jl, k1off); } \
    if ((kt) < 15) { STA2(nb, (kt) + 1, 2); STA2(nb, (kt) + 1, 3); STB2(nb, (kt) + 1, 1); STB2(nb, (kt) + 1, 3); } \
    MM2(0); \
    asm volatile("s_waitcnt lgkmcnt(0)" ::: "memory"); \
    __builtin_amdgcn_sched_barrier(0); \
    __builtin_amdgcn_s_barrier(); \
    /* p1: read B j23(4); stage kt+2 {A0,A1,Br0,Br2} -> b; MFMA j23; vmcnt */ \
    _Pragma("unroll") \
    for (int jl = 2; jl < 4; ++jl) { LDB2(fb[jl][0], b, jl, k0off); LDB2(fb[jl][1], b, jl, k1off); } \
    if ((kt) < 14) { STA2(b, (kt) + 2, 0); STA2(b, (kt) + 2, 1); STB2(b, (kt) + 2, 0); STB2(b, (kt) + 2, 2); } \
    MM2(2); \
    asm volatile("s_waitcnt lgkmcnt(0)" ::: "memory"); \
    __builtin_amdgcn_sched_barrier(0); \
    if ((kt) < 14) { asm volatile("s_waitcnt vmcnt(4)" ::: "memory"); } \
    else           { asm volatile("s_waitcnt vmcnt(0)" ::: "memory"); } \
    __builtin_amdgcn_s_barrier(); \
} while (0)

#pragma unroll 1
    for (int kt2 = 0; kt2 < 16; kt2 += 2) {
        TILE2(kt2, 0, 1);
        TILE2(kt2 + 1, 1, 0);
    }
#undef TILE2
#undef MM2
#undef STA2
#undef STB2
#undef LDA2
#undef LDB2

    const int colL = lane & 15;
    const int rowQ = (lane >> 4) * 4;
#pragma unroll
    for (int jl = 0; jl < 4; ++jl) {
        const int n = n0 + wn * 64 + jl * 16 + colL;
        const float bv = bout[n];
#pragma unroll
        for (int il = 0; il < 4; ++il) {
            const int mbase = m0 + wm * 64 + il * 16 + rowQ;
#pragma unroll
            for (int r = 0; r < 4; ++r)
                Out[(size_t)(mbase + r) * DM + n] = acc[il][jl][r] + bv;
        }
    }
}

extern "C" void kernel_launch(void* const* d_in, const int* in_sizes, int n_in,
                              void* d_out, int out_size, void* d_ws, size_t ws_size,
                              hipStream_t stream) {
    const float* x     = (const float*)d_in[0];   // [4,4096,1024] fp32
    const float* Wproj = (const float*)d_in[1];   // [1024,3072]   fp32
    const float* bproj = (const float*)d_in[2];   // [3072]        fp32
    const float* Wout  = (const float*)d_in[3];   // [1024,1024]   fp32
    const float* bout  = (const float*)d_in[4];   // [1024]        fp32
    float* out = (float*)d_out;                   // [4,4096,1024] fp32 (64 MB)

    unsigned short* Xb  = (unsigned short*)d_out; // shorts [0,16M): Xbf16 (phases 1-3)
    unsigned short* WgT   = (unsigned short*)d_ws;
    unsigned short* WoT   = WgT + MEG;
    unsigned short* WoutT = WgT + 2 * MEG;
    unsigned short* Hws   = WgT + 3 * MEG;

    const bool big_ws = ws_size >= (size_t)19 * MEG * 2;

    unsigned short* Hlo = big_ws ? Hws : ((unsigned short*)d_out + 16 * MEG);
    unsigned short* Hhi = big_ws ? (Hws + (size_t)8192 * DM) : Hws;

    // 1) Xbf16 (d_out lo) <- fp32 x
    conv_x<<<(MTOT * DM) / (256 * 8), 256, 0, stream>>>(x, Xb);

    // 2) transposed bf16 weight panels -> ws
    transpose_w<<<dim3(32, 32, 3), dim3(32, 8, 1), 0, stream>>>(Wproj, Wout, WgT);

    // 3) H = (X@Wg + bg) * sigmoid(X@Wo + bo), stored split across Hlo/Hhi
    gemm1_fused<<<512, 512, 0, stream>>>(Xb, WgT, WoT, bproj, Hlo, Hhi);

    // 4) out = H @ Wout + b_out (128x128 tiles, 2 blocks/CU)
    if (big_ws) {
        gemm2<<<1024, 256, 0, stream>>>(Hlo, Hhi, WoutT, bout, out, 0);
    } else {
        // lo half first (reads d_out-hi H, writes d_out-lo out: disjoint),
        // then hi half (reads only ws, overwrites the now-dead H-lo region)
        gemm2<<<512, 256, 0, stream>>>(Hlo, Hhi, WoutT, bout, out, 0);
        gemm2<<<512, 256, 0, stream>>>(Hlo, Hhi, WoutT, bout, out, 8192);
    }
}